// Round 2
// 338.152 us; speedup vs baseline: 1.0235x; 1.0235x over previous
//
#include <hip/hip_runtime.h>

#define NPOINTS 262144
#define SUMH 224
#define SUMW 221
#define NREG 500

// ---------- DPP helpers ----------
__device__ __forceinline__ float rlane(float v, int l) {
  return __int_as_float(__builtin_amdgcn_readlane(__float_as_int(v), l));
}
template<int CTRL>
__device__ __forceinline__ float dpp0(float x) {   // 0-fill on invalid
  return __int_as_float(__builtin_amdgcn_update_dpp(0, __float_as_int(x), CTRL, 0xF, 0xF, true));
}
template<int CTRL, int RM>
__device__ __forceinline__ float dpp_rm(float x) { // row-masked, old=0
  return __int_as_float(__builtin_amdgcn_update_dpp(0, __float_as_int(x), CTRL, RM, 0xF, false));
}
template<int CTRL>
__device__ __forceinline__ float dpp_max_(float x) {
  return fmaxf(x, __int_as_float(__builtin_amdgcn_update_dpp(__float_as_int(x), __float_as_int(x), CTRL, 0xF, 0xF, false)));
}
// 64-lane reduce / scan (region kernel)
__device__ __forceinline__ float wave_sum(float x) {
  x += dpp0<0x111>(x); x += dpp0<0x112>(x); x += dpp0<0x114>(x); x += dpp0<0x118>(x);
  x += dpp_rm<0x142, 0xA>(x); x += dpp_rm<0x143, 0xC>(x);
  return rlane(x, 63);
}
__device__ __forceinline__ float wave_max(float x) {
  x = dpp_max_<0x111>(x); x = dpp_max_<0x112>(x); x = dpp_max_<0x114>(x);
  x = dpp_max_<0x118>(x); x = dpp_max_<0x142>(x); x = dpp_max_<0x143>(x);
  return rlane(x, 63);
}
__device__ __forceinline__ float wave_scan_incl(float x) {
  x += dpp0<0x111>(x); x += dpp0<0x112>(x); x += dpp0<0x114>(x); x += dpp0<0x118>(x);
  x += dpp_rm<0x142, 0xA>(x);   // row_bcast:15 -> rows 1,3
  x += dpp_rm<0x143, 0xC>(x);   // row_bcast:31 -> rows 2,3
  return x;
}
// 32-lane group sum: 16-lane DPP butterfly + xor16 via ds_swizzle
__device__ __forceinline__ float grp32_sum(float x) {
  x += dpp0<0xB1>(x);    // xor1
  x += dpp0<0x4E>(x);    // xor2
  x += dpp0<0x141>(x);   // row_half_mirror
  x += dpp0<0x140>(x);   // row_mirror
  x += __int_as_float(__builtin_amdgcn_ds_swizzle(__float_as_int(x), 0x401F)); // xor16
  return x;
}
__device__ __forceinline__ float bperm(int byteidx, float v) {
  return __int_as_float(__builtin_amdgcn_ds_bpermute(byteidx, __float_as_int(v)));
}

// ---------- Kernel 1: per-ROI bin-edge table (BL only) ----------
// Per rix (stride SUMH floats), level slots {0..127, 128..191, 192..223}:
//   BL[j] = bin edge j (BL[0]=0, BL[n-1]=1). Widths are recovered in kernel 2
//   as adjacent-edge differences, so no HW/HS tables are needed.
template<int M, int SRC, int DST, int NB>
__device__ __forceinline__ void region_level(const float* __restrict__ wrow,
    float* __restrict__ BL, int lane)
{
  float v0 = (lane < M) ? wrow[SRC + lane] : -1e30f;
  float v1 = -1e30f;
  if constexpr (NB == 128) { if (lane + 64 < M) v1 = wrow[SRC + lane + 64]; }
  float m = wave_max(fmaxf(v0, v1));
  float e0 = __expf(v0 - m);                 // 0 for padded slots
  float e1 = (NB == 128) ? __expf(v1 - m) : 0.0f;
  float sm = wave_sum(e0 + e1);
  float inv = 1.0f / sm;
  float incl0 = wave_scan_incl(e0);
  if (lane == 0) BL[DST] = 0.0f;
  if (lane < M) BL[DST + 1 + lane] = (lane == M - 1) ? 1.0f : incl0 * inv;
  if constexpr (NB == 128) {
    float incl1 = wave_scan_incl(e1) + rlane(incl0, 63);
    int k = 64 + lane;
    if (k < M) BL[DST + 1 + k] = (k == M - 1) ? 1.0f : incl1 * inv;
  }
}

__global__ void __launch_bounds__(64) region_kernel(
    const int* __restrict__ roi, const float* __restrict__ wemb,
    float* __restrict__ wsBL)
{
  int rix = blockIdx.x;
  int lane = threadIdx.x;
  int greg = roi[rix];
  const float* wrow = wemb + (size_t)greg * SUMW;
  float* BL = wsBL + (size_t)rix * SUMH;
  region_level<127,   0,   0, 128>(wrow, BL, lane);
  region_level< 63, 127, 128,  64>(wrow, BL, lane);
  region_level< 31, 190, 192,  32>(wrow, BL, lane);
}

// ---------- Kernel 2: 32-lane groups, 2-deep point pipeline (4 pts/wave) ----------

struct PtState {
  float4 a0, b0, e0;   // level0 (C=4): u, d, bl
  float2 a1, b1, e1;   // level1 (C=2)
  float  a2, b2, e2;   // level2 (C=1)
  float  xv;
  int    pid;
};

__device__ __forceinline__ void load_pt(PtState& P, int pid, int s,
    const float* __restrict__ x, const int* __restrict__ lix,
    const int* __restrict__ roi, const float* __restrict__ delta,
    const float* __restrict__ hemb, const float* __restrict__ wsBL)
{
  P.pid = pid;
  P.xv = x[pid];
  int r = lix[pid];
  int greg = roi[r];
  const float* U  = hemb + (size_t)greg * SUMH;
  const float* D  = delta + (size_t)pid * SUMH;
  const float* BL = wsBL + (size_t)r * SUMH;
  int c0 = s * 4;
  P.a0 = *(const float4*)(U + c0);  P.b0 = *(const float4*)(D + c0);
  P.e0 = *(const float4*)(BL + c0);
  int c1 = 128 + s * 2;
  P.a1 = *(const float2*)(U + c1);  P.b1 = *(const float2*)(D + c1);
  P.e1 = *(const float2*)(BL + c1);
  int c2 = 192 + s;
  P.a2 = U[c2]; P.b2 = D[c2]; P.e2 = BL[c2];
}

// Per-bin trapezoid form: w_i = bl[i+1]-bl[i]; tb_i = 0.5*(he_i+he_{i+1})*w_i.
// area = sum tb; cdf_left(owner bin) = sum tb_i * f[i+1]  (f monotone 1->0).
// The unique owner slot (f[i] && !f[i+1]) holds {hl,hr,loc,w} as a one-hot
// local accumulation; its lane id is recovered uniformly via __ballot + ctz
// and the four values are pulled with ds_bpermute (register-only broadcast —
// no LDS storage, no compiler-invisible cross-lane memory dependence).
template<int C>
__device__ __forceinline__ void apply32(float& xv, float& logdet, int s, int gbase, int nb_idx,
    const float (&u)[C], const float (&d)[C], const float (&bl)[C])
{
  float he[C], f[C];
#pragma unroll
  for (int i = 0; i < C; ++i) he[i] = __expf(u[i] + d[i]);
#pragma unroll
  for (int i = 0; i < C; ++i) f[i] = (bl[i] < xv) ? 1.0f : 0.0f;
  if (s == 0)  f[0]     = 1.0f;   // edge 0 always counted (clamp-low)
  if (s == 31) f[C - 1] = 0.0f;   // last edge never counted (clamp-high)
  // next lane's firsts; cross-group garbage is finite and only reaches
  // slots whose bin weight / flags are forced to zero.
  float fN  = bperm(nb_idx, f[0]);
  float heN = bperm(nb_idx, he[0]);
  float blN = bperm(nb_idx, bl[0]);
  float area = 0.0f, pt = 0.0f;
  float hl = 0.0f, hr = 0.0f, loc = 0.0f, inw = 0.0f;
  bool own = false;
#pragma unroll
  for (int i = 0; i < C; ++i) {
    float fnext  = (i < C - 1) ? f[i + 1]  : fN;
    float henext = (i < C - 1) ? he[i + 1] : heN;
    float blnext = (i < C - 1) ? bl[i + 1] : blN;
    float w = blnext - bl[i];
    if (i == C - 1) w = (s == 31) ? 0.0f : w;   // no bin after the global last edge
    float tb = 0.5f * (he[i] + henext) * w;
    area += tb;
    pt   += tb * fnext;
    float mi = f[i] * (1.0f - fnext);           // exact {0,1}; one-hot across group
    own = own | (mi != 0.0f);
    hl  += he[i]  * mi;
    hr  += henext * mi;
    loc += bl[i]  * mi;
    inw += w      * mi;
  }
  area = grp32_sum(area);
  pt   = grp32_sum(pt);
  // owner lane id (uniform per group) -> pull its registers
  unsigned long long m64 = __ballot(own);
  unsigned gm = gbase ? (unsigned)(m64 >> 32) : (unsigned)m64;
  int ob = ((__builtin_ctz(gm) + gbase) << 2);
  hl  = bperm(ob, hl);
  hr  = bperm(ob, hr);
  loc = bperm(ob, loc);
  inw = bperm(ob, inw);
  float larea = __log2f(area);
  float invarea = __builtin_amdgcn_rcpf(area);
  float alpha = (xv - loc) * __builtin_amdgcn_rcpf(inw);
  float dh = hr - hl;
  xv = ((0.5f * dh * alpha + hl) * alpha * inw + pt) * invarea;
  logdet += (__log2f(alpha * dh + hl) - larea) * 0.69314718055994531f;
}

__device__ __forceinline__ void compute_pt(const PtState& P, int s, int gbase, int nb_idx,
                                           float* __restrict__ out)
{
  float xv = P.xv;
  float logdet = 0.0f;
  {
    float u[4]  = {P.a0.x, P.a0.y, P.a0.z, P.a0.w};
    float d[4]  = {P.b0.x, P.b0.y, P.b0.z, P.b0.w};
    float bl[4] = {P.e0.x, P.e0.y, P.e0.z, P.e0.w};
    apply32<4>(xv, logdet, s, gbase, nb_idx, u, d, bl);
  }
  {
    float u[2]  = {P.a1.x, P.a1.y};
    float d[2]  = {P.b1.x, P.b1.y};
    float bl[2] = {P.e1.x, P.e1.y};
    apply32<2>(xv, logdet, s, gbase, nb_idx, u, d, bl);
  }
  {
    float u[1]  = {P.a2};
    float d[1]  = {P.b2};
    float bl[1] = {P.e2};
    apply32<1>(xv, logdet, s, gbase, nb_idx, u, d, bl);
  }
  if (s == 0) {
    out[P.pid] = xv;
    out[NPOINTS + P.pid] = logdet;
  }
}

__global__ void __launch_bounds__(256, 4) spline_kernel(
    const float* __restrict__ x, const int* __restrict__ roi,
    const int* __restrict__ lix, const float* __restrict__ delta,
    const float* __restrict__ hemb, const float* __restrict__ wsBL,
    float* __restrict__ out)
{
  int tid  = (int)(blockIdx.x * blockDim.x + threadIdx.x);
  int wid  = tid >> 6;
  int lane = (int)(threadIdx.x & 63);
  int grp  = lane >> 5;            // 2 groups per wave
  int s    = lane & 31;            // 32-lane group, lanes <-> columns
  int gbase = lane & 32;           // group base lane within wave
  int base = wid * 4;              // 4 points per wave (2 pipelined pairs)
  int nb_idx = ((lane + 1) & 63) << 2;

  // issue BOTH pairs' load chains before any compute (2-deep pipeline)
  PtState A, B;
  load_pt(A, base + grp,     s, x, lix, roi, delta, hemb, wsBL);
  load_pt(B, base + 2 + grp, s, x, lix, roi, delta, hemb, wsBL);

  compute_pt(A, s, gbase, nb_idx, out);
  compute_pt(B, s, gbase, nb_idx, out);
}

// ---------- launch ----------

extern "C" void kernel_launch(void* const* d_in, const int* in_sizes, int n_in,
                              void* d_out, int out_size, void* d_ws, size_t ws_size,
                              hipStream_t stream) {
  const float* x     = (const float*)d_in[0];
  const int*   roi   = (const int*)  d_in[1];
  const int*   lix   = (const int*)  d_in[2];
  const float* delta = (const float*)d_in[3];
  const float* hemb  = (const float*)d_in[4];
  const float* wemb  = (const float*)d_in[5];

  float* wsBL = (float*)d_ws;                    // [500][224]

  region_kernel<<<NREG, 64, 0, stream>>>(roi, wemb, wsBL);
  spline_kernel<<<NPOINTS / 16, 256, 0, stream>>>(x, roi, lix, delta, hemb,
                                                  wsBL, (float*)d_out);
}